// Round 9
// baseline (648.877 us; speedup 1.0000x reference)
//
#include <hip/hip_runtime.h>
#include <stdint.h>
#include <math.h>

typedef float f32x4 __attribute__((ext_vector_type(4)));
typedef __bf16 bf16x8 __attribute__((ext_vector_type(8)));
typedef unsigned int u32x4 __attribute__((ext_vector_type(4)));
typedef unsigned short u16;

#define DEVINL static __device__ __forceinline__

DEVINL u16 f2bf(float f) {
  union { float f; unsigned u; } x; x.f = f;
  unsigned r = x.u + 0x7fffu + ((x.u >> 16) & 1u);
  return (u16)(r >> 16);
}

DEVINL void gload_lds16(const void* g, void* l) {
  __builtin_amdgcn_global_load_lds(
      (__attribute__((address_space(1))) void*)(g),
      (__attribute__((address_space(3))) void*)(l), 16, 0, 0);
}

// ---- BK=32 tile (128 rows x 32 k, u16), row-pair packed + XOR-swizzled ----
// granule idx (16B): line = idx>>3 (64 lines x 128B), slot = idx&7,
// u = slot ^ (line&7), row = line*2 + (u>>2), c4 = u&3 (k-granule 0..3).
// DMA dest is linear (wave-uniform base + lane*16); swizzle realized via source addr.
DEVINL void stage32(const u16* __restrict__ src0, size_t lda, u16* lds, int w, int lane) {
  #pragma unroll
  for (int h = 0; h < 2; ++h) {
    const int idx = h * 256 + w * 64 + lane;
    const int line = idx >> 3, slot = idx & 7;
    const int u = slot ^ (line & 7);
    const int row = line * 2 + (u >> 2), c4 = u & 3;
    gload_lds16(src0 + (size_t)row * lda + c4 * 8, lds + h * 2048 + w * 512);
  }
}

DEVINL bf16x8 ldfrag(const u16* buf, int row, int kg) {
  const int line = row >> 1;
  const int slot = (((row & 1) * 4 + kg) ^ (line & 7));
  return *(const bf16x8*)((const char*)buf + line * 128 + slot * 16);
}

// ---------------- cast f32 -> bf16 ----------------
__global__ void cast_kernel(const float* __restrict__ src, u16* __restrict__ dst, int n) {
  int i = (blockIdx.x * 256 + threadIdx.x) * 4;
  if (i >= n) return;
  float4 v = *(const float4*)(src + i);
  u16 o[4] = { f2bf(v.x), f2bf(v.y), f2bf(v.z), f2bf(v.w) };
  *(uint64_t*)(dst + i) = *(uint64_t*)o;
}

// ---------------- NT GEMM (small projections): 128x128 tile, BK=64 ----------------
// EPI: 0 = (acc+bias[col])*scale -> bf16 ; 1 = acc+bias[row] -> bf16 (V^T)
//      2 = gelu(acc+bias[col]) -> bf16   ; 3 = prelu(acc+bias[col], alpha[col]) -> f32
template<int EPI>
__global__ __launch_bounds__(256, 2) void gemm_nt(
    const u16* __restrict__ A, int lda, const u16* __restrict__ B, int ldb,
    void* __restrict__ C, int ldc, int coff,
    const float* __restrict__ bias, const float* __restrict__ alpha,
    int N128, int K, float scale)
{
  __shared__ __align__(16) u16 at[2][128 * 64];
  __shared__ __align__(16) u16 bt[2][128 * 64];
  const int tid = threadIdx.x;
  const int w = tid >> 6, lane = tid & 63, r = lane & 15, kg = lane >> 4;
  const int bm = blockIdx.x / N128, bn = blockIdx.x % N128;
  const int m0 = bm * 128, n0 = bn * 128;

  f32x4 acc[4][4];
  #pragma unroll
  for (int m = 0; m < 4; ++m)
    #pragma unroll
    for (int n = 0; n < 4; ++n) acc[m][n] = f32x4{0.f, 0.f, 0.f, 0.f};

  const int srow = tid >> 3, sc = tid & 7;
  const int nk = K >> 6;

  #pragma unroll
  for (int i = 0; i < 4; ++i) {
    int row = srow + i * 32, cs = (sc ^ row) & 7;
    gload_lds16(A + (size_t)(m0 + row) * lda + cs * 8, at[0] + i * 2048 + w * 512);
    gload_lds16(B + (size_t)(n0 + row) * ldb + cs * 8, bt[0] + i * 2048 + w * 512);
  }
  __syncthreads();

  for (int kt = 0; kt < nk; ++kt) {
    const int cur = kt & 1;
    if (kt + 1 < nk) {
      #pragma unroll
      for (int i = 0; i < 4; ++i) {
        int row = srow + i * 32, cs = (sc ^ row) & 7;
        int kcol = (kt + 1) * 64 + cs * 8;
        gload_lds16(A + (size_t)(m0 + row) * lda + kcol, at[cur ^ 1] + i * 2048 + w * 512);
        gload_lds16(B + (size_t)(n0 + row) * ldb + kcol, bt[cur ^ 1] + i * 2048 + w * 512);
      }
    }
    #pragma unroll
    for (int ks = 0; ks < 2; ++ks) {
      bf16x8 af[4], bff[4];
      #pragma unroll
      for (int m = 0; m < 4; ++m) {
        int row = (w >> 1) * 64 + m * 16 + r;
        int cs = ((ks * 4 + kg) ^ row) & 7;
        af[m] = *(const bf16x8*)(at[cur] + row * 64 + cs * 8);
      }
      #pragma unroll
      for (int n = 0; n < 4; ++n) {
        int row = (w & 1) * 64 + n * 16 + r;
        int cs = ((ks * 4 + kg) ^ row) & 7;
        bff[n] = *(const bf16x8*)(bt[cur] + row * 64 + cs * 8);
      }
      #pragma unroll
      for (int m = 0; m < 4; ++m)
        #pragma unroll
        for (int n = 0; n < 4; ++n)
          acc[m][n] = __builtin_amdgcn_mfma_f32_16x16x32_bf16(af[m], bff[n], acc[m][n], 0, 0, 0);
    }
    __syncthreads();
  }

  #pragma unroll
  for (int m = 0; m < 4; ++m) {
    #pragma unroll
    for (int n = 0; n < 4; ++n) {
      const int gcol = n0 + (w & 1) * 64 + n * 16 + r;
      #pragma unroll
      for (int reg = 0; reg < 4; ++reg) {
        const int grow = m0 + (w >> 1) * 64 + m * 16 + kg * 4 + reg;
        float v = acc[m][n][reg];
        if (EPI == 0) v = (v + bias[gcol]) * scale;
        if (EPI == 1) v = v + bias[grow];
        if (EPI == 2) { v += bias[gcol]; v = 0.5f * v * (1.f + erff(v * 0.70710678118654752f)); }
        if (EPI == 3) {
          v += bias[gcol];
          float a = alpha[gcol];
          v = (v >= 0.f) ? v : a * v;
          ((float*)C)[(size_t)grow * ldc + coff + gcol] = v;
        } else {
          ((u16*)C)[(size_t)grow * ldc + coff + gcol] = f2bf(v);
        }
      }
    }
  }
}

// ------- fused S-GEMM: P = exp(D * (Q K^T)), K=512, BK=32, 3 blocks/CU -------
__global__ __launch_bounds__(256, 3) void sgemm_exp(
    const u16* __restrict__ A, const u16* __restrict__ B,
    u16* __restrict__ P, const float* __restrict__ Dmat, float* __restrict__ psum)
{
  __shared__ __align__(16) u16 abuf[2][128 * 32];
  __shared__ __align__(16) u16 bbuf[2][128 * 32];
  const int tid = threadIdx.x;
  const int w = tid >> 6, lane = tid & 63, r = lane & 15, kg = lane >> 4;
  const int xcd = blockIdx.x & 7, i = blockIdx.x >> 3;
  const int bm = (xcd >> 1) * 16 + (i & 15);
  const int bn = (xcd & 1) * 32 + (i >> 4);
  const int m0 = bm * 128, n0 = bn * 128;

  f32x4 acc[4][4];
  #pragma unroll
  for (int m = 0; m < 4; ++m)
    #pragma unroll
    for (int n = 0; n < 4; ++n) acc[m][n] = f32x4{0.f, 0.f, 0.f, 0.f};
  float dreg[64];

  const int gcolb = n0 + (w & 1) * 64 + r;              // + n*16
  const int growb = m0 + (w >> 1) * 64 + kg * 4;        // + m*16 + reg

  stage32(A + (size_t)m0 * 512, 512, abuf[0], w, lane);
  stage32(B + (size_t)n0 * 512, 512, bbuf[0], w, lane);
  __syncthreads();

  #pragma unroll
  for (int kt = 0; kt < 16; ++kt) {
    const int cur = kt & 1;
    if (kt < 15) {
      stage32(A + (size_t)m0 * 512 + (kt + 1) * 32, 512, abuf[cur ^ 1], w, lane);
      stage32(B + (size_t)n0 * 512 + (kt + 1) * 32, 512, bbuf[cur ^ 1], w, lane);
    }
    // D prefetch: 4 statically-indexed loads per kt (64 total)
    #pragma unroll
    for (int q = 0; q < 4; ++q) {
      const int id = kt * 4 + q;
      const int m = id >> 4, n = (id >> 2) & 3, reg = id & 3;
      dreg[id] = __builtin_nontemporal_load(
          Dmat + (size_t)(growb + m * 16 + reg) * 8192 + (gcolb + n * 16));
    }
    bf16x8 af[4], bff[4];
    #pragma unroll
    for (int m = 0; m < 4; ++m) af[m] = ldfrag(abuf[cur], (w >> 1) * 64 + m * 16 + r, kg);
    #pragma unroll
    for (int n = 0; n < 4; ++n) bff[n] = ldfrag(bbuf[cur], (w & 1) * 64 + n * 16 + r, kg);
    #pragma unroll
    for (int m = 0; m < 4; ++m)
      #pragma unroll
      for (int n = 0; n < 4; ++n)
        acc[m][n] = __builtin_amdgcn_mfma_f32_16x16x32_bf16(af[m], bff[n], acc[m][n], 0, 0, 0);
    __syncthreads();
  }

  // epilogue: P = exp(D*S) + deterministic partial row sums
  #pragma unroll
  for (int m = 0; m < 4; ++m) {
    float rs[4] = {0.f, 0.f, 0.f, 0.f};
    #pragma unroll
    for (int n = 0; n < 4; ++n) {
      const int gcol = gcolb + n * 16;
      #pragma unroll
      for (int reg = 0; reg < 4; ++reg) {
        const int grow = growb + m * 16 + reg;
        const float p = __expf(acc[m][n][reg] * dreg[m * 16 + n * 4 + reg]);
        rs[reg] += p;
        P[(size_t)grow * 8192 + gcol] = f2bf(p);
      }
    }
    #pragma unroll
    for (int reg = 0; reg < 4; ++reg) {
      float v = rs[reg];
      v += __shfl_xor(v, 1); v += __shfl_xor(v, 2);
      v += __shfl_xor(v, 4); v += __shfl_xor(v, 8);
      if (r == 0)
        psum[(size_t)(growb + m * 16 + reg) * 128 + bn * 2 + (w & 1)] = v;
    }
  }
}

// ------- PV GEMM, K-split x4, BK=32, 4 blocks/CU -------
// grid 1024: xcd = bid&7; bn = i&3, ks = (i>>2)&3, bm = xcd*8 + (i>>4).
__global__ __launch_bounds__(256, 4) void pv_split(
    const u16* __restrict__ P, const u16* __restrict__ VT, float* __restrict__ Opart)
{
  __shared__ __align__(16) u16 abuf[2][128 * 32];
  __shared__ __align__(16) u16 bbuf[2][128 * 32];
  const int tid = threadIdx.x;
  const int w = tid >> 6, lane = tid & 63, r = lane & 15, kg = lane >> 4;
  const int xcd = blockIdx.x & 7, i = blockIdx.x >> 3;
  const int bn = i & 3, ks = (i >> 2) & 3, bm = xcd * 8 + (i >> 4);
  const int m0 = bm * 128, n0 = bn * 128;
  const int koff = ks * 2048;

  f32x4 acc[4][4];
  #pragma unroll
  for (int m = 0; m < 4; ++m)
    #pragma unroll
    for (int n = 0; n < 4; ++n) acc[m][n] = f32x4{0.f, 0.f, 0.f, 0.f};

  const u16* Pa  = P  + (size_t)m0 * 8192 + koff;
  const u16* Vb  = VT + (size_t)n0 * 8192 + koff;

  stage32(Pa, 8192, abuf[0], w, lane);
  stage32(Vb, 8192, bbuf[0], w, lane);
  __syncthreads();

  for (int kt = 0; kt < 64; ++kt) {
    const int cur = kt & 1;
    if (kt < 63) {
      stage32(Pa + (kt + 1) * 32, 8192, abuf[cur ^ 1], w, lane);
      stage32(Vb + (kt + 1) * 32, 8192, bbuf[cur ^ 1], w, lane);
    }
    bf16x8 af[4], bff[4];
    #pragma unroll
    for (int m = 0; m < 4; ++m) af[m] = ldfrag(abuf[cur], (w >> 1) * 64 + m * 16 + r, kg);
    #pragma unroll
    for (int n = 0; n < 4; ++n) bff[n] = ldfrag(bbuf[cur], (w & 1) * 64 + n * 16 + r, kg);
    #pragma unroll
    for (int m = 0; m < 4; ++m)
      #pragma unroll
      for (int n = 0; n < 4; ++n)
        acc[m][n] = __builtin_amdgcn_mfma_f32_16x16x32_bf16(af[m], bff[n], acc[m][n], 0, 0, 0);
    __syncthreads();
  }

  float* op = Opart + (size_t)ks * 4194304;
  #pragma unroll
  for (int m = 0; m < 4; ++m) {
    #pragma unroll
    for (int n = 0; n < 4; ++n) {
      const int gcol = n0 + (w & 1) * 64 + n * 16 + r;
      #pragma unroll
      for (int reg = 0; reg < 4; ++reg) {
        const int grow = m0 + (w >> 1) * 64 + m * 16 + kg * 4 + reg;
        __builtin_nontemporal_store(acc[m][n][reg], op + (size_t)grow * 512 + gcol);
      }
    }
  }
}

// ---------------- combine 4 PV partials, /lsum, -> bf16 hrb ----------------
__global__ __launch_bounds__(256) void pv_combine(
    const float* __restrict__ Opart, const float* __restrict__ ls, u16* __restrict__ hrb)
{
  const int idx = (blockIdx.x * 256 + threadIdx.x) * 4;
  const int row = idx >> 9;
  const float li = 1.f / ls[row];
  float4 a = *(const float4*)(Opart + idx);
  const float4 b = *(const float4*)(Opart + 4194304 + idx);
  const float4 c = *(const float4*)(Opart + 8388608 + idx);
  const float4 d = *(const float4*)(Opart + 12582912 + idx);
  a.x = (a.x + b.x + c.x + d.x) * li;
  a.y = (a.y + b.y + c.y + d.y) * li;
  a.z = (a.z + b.z + c.z + d.z) * li;
  a.w = (a.w + b.w + c.w + d.w) * li;
  u16 o[4] = { f2bf(a.x), f2bf(a.y), f2bf(a.z), f2bf(a.w) };
  *(uint64_t*)(hrb + idx) = *(uint64_t*)o;
}

// ---------------- reduce psum[8192][128] -> lsum[8192] ----------------
__global__ __launch_bounds__(256) void rowsum_kernel(const float* __restrict__ psum,
                                                     float* __restrict__ ls) {
  const int row = blockIdx.x * 4 + (threadIdx.x >> 6);
  const int lane = threadIdx.x & 63;
  const float2 v = *(const float2*)(psum + (size_t)row * 128 + lane * 2);
  float s = v.x + v.y;
  #pragma unroll
  for (int m = 1; m < 64; m <<= 1) s += __shfl_xor(s, m);
  if (lane == 0) ls[row] = s;
}

// ---------------- GroupNorm ----------------
__global__ void gn_stats_kernel(const float* __restrict__ x, float* __restrict__ part) {
  const int g = blockIdx.x >> 4, ch = blockIdx.x & 15;
  const int t = threadIdx.x;
  float s = 0.f, ss = 0.f;
  const int cl = (t & 7) * 4;
  const int r0 = ch * 512 + (t >> 3);
  for (int i = 0; i < 16; ++i) {
    const float4 v = *(const float4*)(x + (size_t)(r0 + i * 32) * 512 + g * 32 + cl);
    s += v.x + v.y + v.z + v.w;
    ss += v.x * v.x + v.y * v.y + v.z * v.z + v.w * v.w;
  }
  #pragma unroll
  for (int m = 1; m < 64; m <<= 1) { s += __shfl_xor(s, m); ss += __shfl_xor(ss, m); }
  __shared__ float red[8];
  const int w = t >> 6, lane = t & 63;
  if (lane == 0) { red[w * 2] = s; red[w * 2 + 1] = ss; }
  __syncthreads();
  if (t == 0) {
    part[blockIdx.x * 2]     = red[0] + red[2] + red[4] + red[6];
    part[blockIdx.x * 2 + 1] = red[1] + red[3] + red[5] + red[7];
  }
}

__global__ void gn_finalize_kernel(const float* __restrict__ part, float* __restrict__ mv) {
  const int g = threadIdx.x;
  if (g < 16) {
    float s = 0.f, ss = 0.f;
    for (int ch = 0; ch < 16; ++ch) {
      s  += part[(g * 16 + ch) * 2];
      ss += part[(g * 16 + ch) * 2 + 1];
    }
    const float mean = s * (1.f / 262144.f);
    const float var = ss * (1.f / 262144.f) - mean * mean;
    mv[g * 2] = mean;
    mv[g * 2 + 1] = rsqrtf(var + 1e-5f);
  }
}

__global__ void gn_norm_kernel(const float* __restrict__ x, const float* __restrict__ mv,
                               const float* __restrict__ gamma, const float* __restrict__ beta,
                               float* __restrict__ out) {
  const int idx = (blockIdx.x * 256 + threadIdx.x) * 4;
  const int c = idx & 511, g = c >> 5;
  const float mean = mv[g * 2], rs = mv[g * 2 + 1];
  float4 v = *(const float4*)(x + idx);
  const float4 gm = *(const float4*)(gamma + c);
  const float4 bt = *(const float4*)(beta + c);
  v.x = (v.x - mean) * rs * gm.x + bt.x;
  v.y = (v.y - mean) * rs * gm.y + bt.y;
  v.z = (v.z - mean) * rs * gm.z + bt.z;
  v.w = (v.w - mean) * rs * gm.w + bt.w;
  *(float4*)(out + idx) = v;
}

// ---------------- launch ----------------
// ws plan (~1GB available):
//  [0,128M)   P bf16 8192x8192; hb [0,16M) steps1-2; xcat [0,32M) steps5-6; xf [32,48M) steps6-7
//  [128,144M) hpb ; [144,152M) Qb then hrb ; [152,160M) Kb ; [160,168M) VTb
//  [168M..)   weights, lsum, gp, mv ; [176,180M) psum ; [184,248M) Opart f32 x4
extern "C" void kernel_launch(void* const* d_in, const int* in_sizes, int n_in,
                              void* d_out, int out_size, void* d_ws, size_t ws_size,
                              hipStream_t stream) {
  (void)in_sizes; (void)n_in; (void)out_size; (void)ws_size;
  const float* h     = (const float*)d_in[0];
  const float* Dm    = (const float*)d_in[1];
  const float* hp    = (const float*)d_in[2];
  const float* Wq    = (const float*)d_in[3];
  const float* bq    = (const float*)d_in[4];
  const float* Wk    = (const float*)d_in[5];
  const float* bk    = (const float*)d_in[6];
  const float* Wv    = (const float*)d_in[7];
  const float* bv    = (const float*)d_in[8];
  const float* Wr    = (const float*)d_in[9];
  const float* br    = (const float*)d_in[10];
  const float* Wc    = (const float*)d_in[11];
  const float* bc    = (const float*)d_in[12];
  const float* Wp    = (const float*)d_in[13];
  const float* bp    = (const float*)d_in[14];
  const float* alpha = (const float*)d_in[15];
  const float* gamma = (const float*)d_in[16];
  const float* beta  = (const float*)d_in[17];

  char* ws = (char*)d_ws;
  const size_t MB = 1ull << 20;
  u16*   P    = (u16*)(ws);                 // 128 MB
  u16*   hb   = (u16*)(ws);                 // 16 MB transient
  u16*   xcat = (u16*)(ws);                 // 32 MB transient
  float* xf   = (float*)(ws + 32 * MB);     // 16 MB
  u16*   hpb  = (u16*)(ws + 128 * MB);
  u16*   Qb   = (u16*)(ws + 144 * MB);
  u16*   hrb  = (u16*)(ws + 144 * MB);      // reuses Qb slot after S-GEMM
  u16*   Kb   = (u16*)(ws + 152 * MB);
  u16*   VTb  = (u16*)(ws + 160 * MB);
  u16*   Wqb  = (u16*)(ws + 168 * MB);
  u16*   Wkb  = Wqb + 262144;
  u16*   Wvb  = Wkb + 262144;
  u16*   Wrb  = Wvb + 262144;
  u16*   Wcb  = Wrb + 524288;
  u16*   Wpb  = Wcb + 524288;
  float* lsum = (float*)(ws + 168 * MB + 5767168);
  float* gp   = lsum + 8192;
  float* mv   = gp + 512;
  float* psum = (float*)(ws + 176 * MB);    // 4 MB
  float* Opart = (float*)(ws + 184 * MB);   // 64 MB

  // 1. casts
  cast_kernel<<<4096, 256, 0, stream>>>(h, hb, 4194304);
  cast_kernel<<<4096, 256, 0, stream>>>(hp, hpb, 4194304);
  cast_kernel<<<256, 256, 0, stream>>>(Wq, Wqb, 262144);
  cast_kernel<<<256, 256, 0, stream>>>(Wk, Wkb, 262144);
  cast_kernel<<<256, 256, 0, stream>>>(Wv, Wvb, 262144);
  cast_kernel<<<512, 256, 0, stream>>>(Wr, Wrb, 524288);
  cast_kernel<<<512, 256, 0, stream>>>(Wc, Wcb, 524288);
  cast_kernel<<<1024, 256, 0, stream>>>(Wp, Wpb, 1048576);

  // 2. Q = (h Wq^T + bq)/sqrt(512) ; K = h Wk^T + bk ; V^T = Wv h^T + bv (row bias)
  gemm_nt<0><<<256, 256, 0, stream>>>(hb, 512, Wqb, 512, Qb, 512, 0, bq, nullptr, 4, 512, 0.044194173824159216f);
  gemm_nt<0><<<256, 256, 0, stream>>>(hb, 512, Wkb, 512, Kb, 512, 0, bk, nullptr, 4, 512, 1.0f);
  gemm_nt<1><<<256, 256, 0, stream>>>(Wvb, 512, hb, 512, VTb, 8192, 0, bv, nullptr, 64, 512, 1.0f);

  // 3. P = exp(D * (Q K^T)) fused; psum partials (scale folded into Q)
  sgemm_exp<<<4096, 256, 0, stream>>>(Qb, Kb, P, Dm, psum);
  rowsum_kernel<<<2048, 256, 0, stream>>>(psum, lsum);

  // 4. PV K-split x4 -> f32 partials ; combine (/lsum) -> bf16 h_ret
  pv_split<<<1024, 256, 0, stream>>>(P, VTb, Opart);
  pv_combine<<<4096, 256, 0, stream>>>(Opart, lsum, hrb);

  // 5. xcat[:, :1024] = gelu(h_ret Wr^T + br) ; xcat[:, 1024:] = h' Wc^T + bc
  gemm_nt<2><<<512, 256, 0, stream>>>(hrb, 512, Wrb, 512, xcat, 2048, 0, br, nullptr, 8, 512, 1.0f);
  gemm_nt<0><<<512, 256, 0, stream>>>(hpb, 512, Wcb, 512, xcat, 2048, 1024, bc, nullptr, 8, 512, 1.0f);

  // 6. x = prelu(xcat Wp^T + bp) (f32)
  gemm_nt<3><<<256, 256, 0, stream>>>(xcat, 2048, Wpb, 2048, xf, 512, 0, bp, alpha, 4, 2048, 1.0f);

  // 7. GroupNorm
  gn_stats_kernel<<<256, 256, 0, stream>>>(xf, gp);
  gn_finalize_kernel<<<1, 64, 0, stream>>>(gp, mv);
  gn_norm_kernel<<<4096, 256, 0, stream>>>(xf, mv, gamma, beta, (float*)d_out);
}

// Round 10
// 404.950 us; speedup vs baseline: 1.6024x; 1.6024x over previous
//
#include <hip/hip_runtime.h>
#include <stdint.h>
#include <math.h>

typedef float f32x4 __attribute__((ext_vector_type(4)));
typedef __bf16 bf16x8 __attribute__((ext_vector_type(8)));
typedef unsigned int u32x4 __attribute__((ext_vector_type(4)));
typedef unsigned short u16;

#define DEVINL static __device__ __forceinline__

DEVINL u16 f2bf(float f) {
  union { float f; unsigned u; } x; x.f = f;
  unsigned r = x.u + 0x7fffu + ((x.u >> 16) & 1u);
  return (u16)(r >> 16);
}

DEVINL void gload_lds16(const void* g, void* l) {
  __builtin_amdgcn_global_load_lds(
      (__attribute__((address_space(1))) void*)(g),
      (__attribute__((address_space(3))) void*)(l), 16, 0, 0);
}

// ---------------- cast f32 -> bf16 ----------------
__global__ void cast_kernel(const float* __restrict__ src, u16* __restrict__ dst, int n) {
  int i = (blockIdx.x * 256 + threadIdx.x) * 4;
  if (i >= n) return;
  float4 v = *(const float4*)(src + i);
  u16 o[4] = { f2bf(v.x), f2bf(v.y), f2bf(v.z), f2bf(v.w) };
  *(uint64_t*)(dst + i) = *(uint64_t*)o;
}

// ---------------- NT GEMM: C[M,N] = A[M,K] @ B[N,K]^T, 128x128 tile, BK=64 ----------------
// EPI: 0 = (acc+bias[col])*scale -> bf16 ; 1 = acc+bias[row] -> bf16 (V^T)
//      2 = gelu(acc+bias[col]) -> bf16   ; 3 = prelu(acc+bias[col], alpha[col]) -> f32
template<int EPI>
__global__ __launch_bounds__(256, 2) void gemm_nt(
    const u16* __restrict__ A, int lda, const u16* __restrict__ B, int ldb,
    void* __restrict__ C, int ldc, int coff,
    const float* __restrict__ bias, const float* __restrict__ alpha,
    int N128, int K, float scale)
{
  __shared__ __align__(16) u16 at[2][128 * 64];
  __shared__ __align__(16) u16 bt[2][128 * 64];
  const int tid = threadIdx.x;
  const int w = tid >> 6, lane = tid & 63, r = lane & 15, kg = lane >> 4;
  const int bm = blockIdx.x / N128, bn = blockIdx.x % N128;
  const int m0 = bm * 128, n0 = bn * 128;

  f32x4 acc[4][4];
  #pragma unroll
  for (int m = 0; m < 4; ++m)
    #pragma unroll
    for (int n = 0; n < 4; ++n) acc[m][n] = f32x4{0.f, 0.f, 0.f, 0.f};

  const int srow = tid >> 3, sc = tid & 7;
  const int nk = K >> 6;

  #pragma unroll
  for (int i = 0; i < 4; ++i) {
    int row = srow + i * 32, cs = (sc ^ row) & 7;
    gload_lds16(A + (size_t)(m0 + row) * lda + cs * 8, at[0] + i * 2048 + w * 512);
    gload_lds16(B + (size_t)(n0 + row) * ldb + cs * 8, bt[0] + i * 2048 + w * 512);
  }
  __syncthreads();

  for (int kt = 0; kt < nk; ++kt) {
    const int cur = kt & 1;
    if (kt + 1 < nk) {
      #pragma unroll
      for (int i = 0; i < 4; ++i) {
        int row = srow + i * 32, cs = (sc ^ row) & 7;
        int kcol = (kt + 1) * 64 + cs * 8;
        gload_lds16(A + (size_t)(m0 + row) * lda + kcol, at[cur ^ 1] + i * 2048 + w * 512);
        gload_lds16(B + (size_t)(n0 + row) * ldb + kcol, bt[cur ^ 1] + i * 2048 + w * 512);
      }
    }
    #pragma unroll
    for (int ks = 0; ks < 2; ++ks) {
      bf16x8 af[4], bff[4];
      #pragma unroll
      for (int m = 0; m < 4; ++m) {
        int row = (w >> 1) * 64 + m * 16 + r;
        int cs = ((ks * 4 + kg) ^ row) & 7;
        af[m] = *(const bf16x8*)(at[cur] + row * 64 + cs * 8);
      }
      #pragma unroll
      for (int n = 0; n < 4; ++n) {
        int row = (w & 1) * 64 + n * 16 + r;
        int cs = ((ks * 4 + kg) ^ row) & 7;
        bff[n] = *(const bf16x8*)(bt[cur] + row * 64 + cs * 8);
      }
      #pragma unroll
      for (int m = 0; m < 4; ++m)
        #pragma unroll
        for (int n = 0; n < 4; ++n)
          acc[m][n] = __builtin_amdgcn_mfma_f32_16x16x32_bf16(af[m], bff[n], acc[m][n], 0, 0, 0);
    }
    __syncthreads();
  }

  #pragma unroll
  for (int m = 0; m < 4; ++m) {
    #pragma unroll
    for (int n = 0; n < 4; ++n) {
      const int gcol = n0 + (w & 1) * 64 + n * 16 + r;
      #pragma unroll
      for (int reg = 0; reg < 4; ++reg) {
        const int grow = m0 + (w >> 1) * 64 + m * 16 + kg * 4 + reg;
        float v = acc[m][n][reg];
        if (EPI == 0) v = (v + bias[gcol]) * scale;
        if (EPI == 1) v = v + bias[grow];
        if (EPI == 2) { v += bias[gcol]; v = 0.5f * v * (1.f + erff(v * 0.70710678118654752f)); }
        if (EPI == 3) {
          v += bias[gcol];
          float a = alpha[gcol];
          v = (v >= 0.f) ? v : a * v;
          ((float*)C)[(size_t)grow * ldc + coff + gcol] = v;
        } else {
          ((u16*)C)[(size_t)grow * ldc + coff + gcol] = f2bf(v);
        }
      }
    }
  }
}

// ------- fused S-GEMM: P = exp(D * (Q K^T)), K=512, BK=64, 2 blocks/CU -------
// D prefetch: 8 loads issued at top of each kt body, PINNED live at the end of the
// body via asm ("+v") so the vmcnt wait lands after staging+MFMA (latency covered)
// and the values stay register-resident to the epilogue (no sinking, no spill).
__global__ __launch_bounds__(256, 2) void sgemm_exp(
    const u16* __restrict__ A, const u16* __restrict__ B,
    u16* __restrict__ P, const float* __restrict__ Dmat, float* __restrict__ psum)
{
  __shared__ __align__(16) u16 at[2][128 * 64];
  __shared__ __align__(16) u16 bt[2][128 * 64];
  const int tid = threadIdx.x;
  const int w = tid >> 6, lane = tid & 63, r = lane & 15, kg = lane >> 4;
  const int xcd = blockIdx.x & 7, i = blockIdx.x >> 3;
  const int bm = (xcd >> 1) * 16 + (i & 15);
  const int bn = (xcd & 1) * 32 + (i >> 4);
  const int m0 = bm * 128, n0 = bn * 128;

  f32x4 acc[4][4];
  #pragma unroll
  for (int m = 0; m < 4; ++m)
    #pragma unroll
    for (int n = 0; n < 4; ++n) acc[m][n] = f32x4{0.f, 0.f, 0.f, 0.f};
  float dreg[64];

  const int srow = tid >> 3, sc = tid & 7;
  const int gcolb = n0 + (w & 1) * 64 + r;              // + n*16
  const int growb = m0 + (w >> 1) * 64 + kg * 4;        // + m*16 + reg

  #pragma unroll
  for (int ii = 0; ii < 4; ++ii) {
    int row = srow + ii * 32, cs = (sc ^ row) & 7;
    gload_lds16(A + (size_t)(m0 + row) * 512 + cs * 8, at[0] + ii * 2048 + w * 512);
    gload_lds16(B + (size_t)(n0 + row) * 512 + cs * 8, bt[0] + ii * 2048 + w * 512);
  }
  __syncthreads();

  #pragma unroll
  for (int kt = 0; kt < 8; ++kt) {
    const int cur = kt & 1;
    // issue D prefetch batch for this kt (8 statically-indexed loads)
    #pragma unroll
    for (int q = 0; q < 8; ++q) {
      const int id = kt * 8 + q;
      const int m = id >> 4, n = (id >> 2) & 3, reg = id & 3;
      dreg[id] = __builtin_nontemporal_load(
          Dmat + (size_t)(growb + m * 16 + reg) * 8192 + (gcolb + n * 16));
    }
    if (kt < 7) {
      #pragma unroll
      for (int ii = 0; ii < 4; ++ii) {
        int row = srow + ii * 32, cs = (sc ^ row) & 7;
        int kcol = (kt + 1) * 64 + cs * 8;
        gload_lds16(A + (size_t)(m0 + row) * 512 + kcol, at[cur ^ 1] + ii * 2048 + w * 512);
        gload_lds16(B + (size_t)(n0 + row) * 512 + kcol, bt[cur ^ 1] + ii * 2048 + w * 512);
      }
    }
    #pragma unroll
    for (int ks = 0; ks < 2; ++ks) {
      bf16x8 af[4], bff[4];
      #pragma unroll
      for (int m = 0; m < 4; ++m) {
        int row = (w >> 1) * 64 + m * 16 + r;
        int cs = ((ks * 4 + kg) ^ row) & 7;
        af[m] = *(const bf16x8*)(at[cur] + row * 64 + cs * 8);
      }
      #pragma unroll
      for (int n = 0; n < 4; ++n) {
        int row = (w & 1) * 64 + n * 16 + r;
        int cs = ((ks * 4 + kg) ^ row) & 7;
        bff[n] = *(const bf16x8*)(bt[cur] + row * 64 + cs * 8);
      }
      #pragma unroll
      for (int m = 0; m < 4; ++m)
        #pragma unroll
        for (int n = 0; n < 4; ++n)
          acc[m][n] = __builtin_amdgcn_mfma_f32_16x16x32_bf16(af[m], bff[n], acc[m][n], 0, 0, 0);
    }
    // pin this kt's D batch: forces the loads to have issued above (wait lands
    // here, after the MFMA cluster) and keeps values in VGPRs until epilogue.
    #pragma unroll
    for (int q = 0; q < 8; ++q)
      asm volatile("" : "+v"(dreg[kt * 8 + q]));
    __syncthreads();
  }

  // epilogue: P = exp(D*S) + deterministic partial row sums
  #pragma unroll
  for (int m = 0; m < 4; ++m) {
    float rs[4] = {0.f, 0.f, 0.f, 0.f};
    #pragma unroll
    for (int n = 0; n < 4; ++n) {
      const int gcol = gcolb + n * 16;
      #pragma unroll
      for (int reg = 0; reg < 4; ++reg) {
        const int grow = growb + m * 16 + reg;
        const float p = __expf(acc[m][n][reg] * dreg[m * 16 + n * 4 + reg]);
        rs[reg] += p;
        P[(size_t)grow * 8192 + gcol] = f2bf(p);
      }
    }
    #pragma unroll
    for (int reg = 0; reg < 4; ++reg) {
      float v = rs[reg];
      v += __shfl_xor(v, 1); v += __shfl_xor(v, 2);
      v += __shfl_xor(v, 4); v += __shfl_xor(v, 8);
      if (r == 0)
        psum[(size_t)(growb + m * 16 + reg) * 128 + bn * 2 + (w & 1)] = v;
    }
  }
}

// ------- PV GEMM, K-split x4, BK=64: Opart[ks] = P[:,ks*2048:+2048] @ V-slice -------
// grid 1024: xcd = bid&7; bn = i&3, ks = (i>>2)&3, bm = xcd*8 + (i>>4).
__global__ __launch_bounds__(256, 2) void pv_split(
    const u16* __restrict__ P, const u16* __restrict__ VT, float* __restrict__ Opart)
{
  __shared__ __align__(16) u16 at[2][128 * 64];
  __shared__ __align__(16) u16 bt[2][128 * 64];
  const int tid = threadIdx.x;
  const int w = tid >> 6, lane = tid & 63, r = lane & 15, kg = lane >> 4;
  const int xcd = blockIdx.x & 7, i = blockIdx.x >> 3;
  const int bn = i & 3, ks = (i >> 2) & 3, bm = xcd * 8 + (i >> 4);
  const int m0 = bm * 128, n0 = bn * 128;
  const int koff = ks * 2048;

  f32x4 acc[4][4];
  #pragma unroll
  for (int m = 0; m < 4; ++m)
    #pragma unroll
    for (int n = 0; n < 4; ++n) acc[m][n] = f32x4{0.f, 0.f, 0.f, 0.f};

  const int srow = tid >> 3, sc = tid & 7;

  #pragma unroll
  for (int ii = 0; ii < 4; ++ii) {
    int row = srow + ii * 32, cs = (sc ^ row) & 7;
    gload_lds16(P  + (size_t)(m0 + row) * 8192 + koff + cs * 8, at[0] + ii * 2048 + w * 512);
    gload_lds16(VT + (size_t)(n0 + row) * 8192 + koff + cs * 8, bt[0] + ii * 2048 + w * 512);
  }
  __syncthreads();

  for (int kt = 0; kt < 32; ++kt) {
    const int cur = kt & 1;
    if (kt < 31) {
      #pragma unroll
      for (int ii = 0; ii < 4; ++ii) {
        int row = srow + ii * 32, cs = (sc ^ row) & 7;
        int kcol = koff + (kt + 1) * 64 + cs * 8;
        gload_lds16(P  + (size_t)(m0 + row) * 8192 + kcol, at[cur ^ 1] + ii * 2048 + w * 512);
        gload_lds16(VT + (size_t)(n0 + row) * 8192 + kcol, bt[cur ^ 1] + ii * 2048 + w * 512);
      }
    }
    #pragma unroll
    for (int ks2 = 0; ks2 < 2; ++ks2) {
      bf16x8 af[4], bff[4];
      #pragma unroll
      for (int m = 0; m < 4; ++m) {
        int row = (w >> 1) * 64 + m * 16 + r;
        int cs = ((ks2 * 4 + kg) ^ row) & 7;
        af[m] = *(const bf16x8*)(at[cur] + row * 64 + cs * 8);
      }
      #pragma unroll
      for (int n = 0; n < 4; ++n) {
        int row = (w & 1) * 64 + n * 16 + r;
        int cs = ((ks2 * 4 + kg) ^ row) & 7;
        bff[n] = *(const bf16x8*)(bt[cur] + row * 64 + cs * 8);
      }
      #pragma unroll
      for (int m = 0; m < 4; ++m)
        #pragma unroll
        for (int n = 0; n < 4; ++n)
          acc[m][n] = __builtin_amdgcn_mfma_f32_16x16x32_bf16(af[m], bff[n], acc[m][n], 0, 0, 0);
    }
    __syncthreads();
  }

  float* op = Opart + (size_t)ks * 4194304;
  #pragma unroll
  for (int m = 0; m < 4; ++m) {
    #pragma unroll
    for (int n = 0; n < 4; ++n) {
      const int gcol = n0 + (w & 1) * 64 + n * 16 + r;
      #pragma unroll
      for (int reg = 0; reg < 4; ++reg) {
        const int grow = m0 + (w >> 1) * 64 + m * 16 + kg * 4 + reg;
        __builtin_nontemporal_store(acc[m][n][reg], op + (size_t)grow * 512 + gcol);
      }
    }
  }
}

// ---------------- combine 4 PV partials, /lsum, -> bf16 hrb ----------------
__global__ __launch_bounds__(256) void pv_combine(
    const float* __restrict__ Opart, const float* __restrict__ ls, u16* __restrict__ hrb)
{
  const int idx = (blockIdx.x * 256 + threadIdx.x) * 4;
  const int row = idx >> 9;
  const float li = 1.f / ls[row];
  float4 a = *(const float4*)(Opart + idx);
  const float4 b = *(const float4*)(Opart + 4194304 + idx);
  const float4 c = *(const float4*)(Opart + 8388608 + idx);
  const float4 d = *(const float4*)(Opart + 12582912 + idx);
  a.x = (a.x + b.x + c.x + d.x) * li;
  a.y = (a.y + b.y + c.y + d.y) * li;
  a.z = (a.z + b.z + c.z + d.z) * li;
  a.w = (a.w + b.w + c.w + d.w) * li;
  u16 o[4] = { f2bf(a.x), f2bf(a.y), f2bf(a.z), f2bf(a.w) };
  *(uint64_t*)(hrb + idx) = *(uint64_t*)o;
}

// ---------------- reduce psum[8192][128] -> lsum[8192] ----------------
__global__ __launch_bounds__(256) void rowsum_kernel(const float* __restrict__ psum,
                                                     float* __restrict__ ls) {
  const int row = blockIdx.x * 4 + (threadIdx.x >> 6);
  const int lane = threadIdx.x & 63;
  const float2 v = *(const float2*)(psum + (size_t)row * 128 + lane * 2);
  float s = v.x + v.y;
  #pragma unroll
  for (int m = 1; m < 64; m <<= 1) s += __shfl_xor(s, m);
  if (lane == 0) ls[row] = s;
}

// ---------------- GroupNorm ----------------
__global__ void gn_stats_kernel(const float* __restrict__ x, float* __restrict__ part) {
  const int g = blockIdx.x >> 4, ch = blockIdx.x & 15;
  const int t = threadIdx.x;
  float s = 0.f, ss = 0.f;
  const int cl = (t & 7) * 4;
  const int r0 = ch * 512 + (t >> 3);
  for (int i = 0; i < 16; ++i) {
    const float4 v = *(const float4*)(x + (size_t)(r0 + i * 32) * 512 + g * 32 + cl);
    s += v.x + v.y + v.z + v.w;
    ss += v.x * v.x + v.y * v.y + v.z * v.z + v.w * v.w;
  }
  #pragma unroll
  for (int m = 1; m < 64; m <<= 1) { s += __shfl_xor(s, m); ss += __shfl_xor(ss, m); }
  __shared__ float red[8];
  const int w = t >> 6, lane = t & 63;
  if (lane == 0) { red[w * 2] = s; red[w * 2 + 1] = ss; }
  __syncthreads();
  if (t == 0) {
    part[blockIdx.x * 2]     = red[0] + red[2] + red[4] + red[6];
    part[blockIdx.x * 2 + 1] = red[1] + red[3] + red[5] + red[7];
  }
}

__global__ void gn_finalize_kernel(const float* __restrict__ part, float* __restrict__ mv) {
  const int g = threadIdx.x;
  if (g < 16) {
    float s = 0.f, ss = 0.f;
    for (int ch = 0; ch < 16; ++ch) {
      s  += part[(g * 16 + ch) * 2];
      ss += part[(g * 16 + ch) * 2 + 1];
    }
    const float mean = s * (1.f / 262144.f);
    const float var = ss * (1.f / 262144.f) - mean * mean;
    mv[g * 2] = mean;
    mv[g * 2 + 1] = rsqrtf(var + 1e-5f);
  }
}

__global__ void gn_norm_kernel(const float* __restrict__ x, const float* __restrict__ mv,
                               const float* __restrict__ gamma, const float* __restrict__ beta,
                               float* __restrict__ out) {
  const int idx = (blockIdx.x * 256 + threadIdx.x) * 4;
  const int c = idx & 511, g = c >> 5;
  const float mean = mv[g * 2], rs = mv[g * 2 + 1];
  float4 v = *(const float4*)(x + idx);
  const float4 gm = *(const float4*)(gamma + c);
  const float4 bt = *(const float4*)(beta + c);
  v.x = (v.x - mean) * rs * gm.x + bt.x;
  v.y = (v.y - mean) * rs * gm.y + bt.y;
  v.z = (v.z - mean) * rs * gm.z + bt.z;
  v.w = (v.w - mean) * rs * gm.w + bt.w;
  *(float4*)(out + idx) = v;
}

// ---------------- launch ----------------
// ws plan (~1GB available):
//  [0,128M)   P bf16 8192x8192; hb [0,16M) steps1-2; xcat [0,32M) steps5-6; xf [32,48M) steps6-7
//  [128,144M) hpb ; [144,152M) Qb then hrb ; [152,160M) Kb ; [160,168M) VTb
//  [168M..)   weights, lsum, gp, mv ; [176,180M) psum ; [184,248M) Opart f32 x4
extern "C" void kernel_launch(void* const* d_in, const int* in_sizes, int n_in,
                              void* d_out, int out_size, void* d_ws, size_t ws_size,
                              hipStream_t stream) {
  (void)in_sizes; (void)n_in; (void)out_size; (void)ws_size;
  const float* h     = (const float*)d_in[0];
  const float* Dm    = (const float*)d_in[1];
  const float* hp    = (const float*)d_in[2];
  const float* Wq    = (const float*)d_in[3];
  const float* bq    = (const float*)d_in[4];
  const float* Wk    = (const float*)d_in[5];
  const float* bk    = (const float*)d_in[6];
  const float* Wv    = (const float*)d_in[7];
  const float* bv    = (const float*)d_in[8];
  const float* Wr    = (const float*)d_in[9];
  const float* br    = (const float*)d_in[10];
  const float* Wc    = (const float*)d_in[11];
  const float* bc    = (const float*)d_in[12];
  const float* Wp    = (const float*)d_in[13];
  const float* bp    = (const float*)d_in[14];
  const float* alpha = (const float*)d_in[15];
  const float* gamma = (const float*)d_in[16];
  const float* beta  = (const float*)d_in[17];

  char* ws = (char*)d_ws;
  const size_t MB = 1ull << 20;
  u16*   P    = (u16*)(ws);                 // 128 MB
  u16*   hb   = (u16*)(ws);                 // 16 MB transient
  u16*   xcat = (u16*)(ws);                 // 32 MB transient
  float* xf   = (float*)(ws + 32 * MB);     // 16 MB
  u16*   hpb  = (u16*)(ws + 128 * MB);
  u16*   Qb   = (u16*)(ws + 144 * MB);
  u16*   hrb  = (u16*)(ws + 144 * MB);      // reuses Qb slot after S-GEMM
  u16*   Kb   = (u16*)(ws + 152 * MB);
  u16*   VTb  = (u16*)(ws + 160 * MB);
  u16*   Wqb  = (u16*)(ws + 168 * MB);
  u16*   Wkb  = Wqb + 262144;
  u16*   Wvb  = Wkb + 262144;
  u16*   Wrb  = Wvb + 262144;
  u16*   Wcb  = Wrb + 524288;
  u16*   Wpb  = Wcb + 524288;
  float* lsum = (float*)(ws + 168 * MB + 5767168);
  float* gp   = lsum + 8192;
  float* mv   = gp + 512;
  float* psum = (float*)(ws + 176 * MB);    // 4 MB
  float* Opart = (float*)(ws + 184 * MB);   // 64 MB

  // 1. casts
  cast_kernel<<<4096, 256, 0, stream>>>(h, hb, 4194304);
  cast_kernel<<<4096, 256, 0, stream>>>(hp, hpb, 4194304);
  cast_kernel<<<256, 256, 0, stream>>>(Wq, Wqb, 262144);
  cast_kernel<<<256, 256, 0, stream>>>(Wk, Wkb, 262144);
  cast_kernel<<<256, 256, 0, stream>>>(Wv, Wvb, 262144);
  cast_kernel<<<512, 256, 0, stream>>>(Wr, Wrb, 524288);
  cast_kernel<<<512, 256, 0, stream>>>(Wc, Wcb, 524288);
  cast_kernel<<<1024, 256, 0, stream>>>(Wp, Wpb, 1048576);

  // 2. Q = (h Wq^T + bq)/sqrt(512) ; K = h Wk^T + bk ; V^T = Wv h^T + bv (row bias)
  gemm_nt<0><<<256, 256, 0, stream>>>(hb, 512, Wqb, 512, Qb, 512, 0, bq, nullptr, 4, 512, 0.044194173824159216f);
  gemm_nt<0><<<256, 256, 0, stream>>>(hb, 512, Wkb, 512, Kb, 512, 0, bk, nullptr, 4, 512, 1.0f);
  gemm_nt<1><<<256, 256, 0, stream>>>(Wvb, 512, hb, 512, VTb, 8192, 0, bv, nullptr, 64, 512, 1.0f);

  // 3. P = exp(D * (Q K^T)) fused; psum partials (scale folded into Q)
  sgemm_exp<<<4096, 256, 0, stream>>>(Qb, Kb, P, Dm, psum);
  rowsum_kernel<<<2048, 256, 0, stream>>>(psum, lsum);

  // 4. PV K-split x4 -> f32 partials ; combine (/lsum) -> bf16 h_ret
  pv_split<<<1024, 256, 0, stream>>>(P, VTb, Opart);
  pv_combine<<<4096, 256, 0, stream>>>(Opart, lsum, hrb);

  // 5. xcat[:, :1024] = gelu(h_ret Wr^T + br) ; xcat[:, 1024:] = h' Wc^T + bc
  gemm_nt<2><<<512, 256, 0, stream>>>(hrb, 512, Wrb, 512, xcat, 2048, 0, br, nullptr, 8, 512, 1.0f);
  gemm_nt<0><<<512, 256, 0, stream>>>(hpb, 512, Wcb, 512, xcat, 2048, 1024, bc, nullptr, 8, 512, 1.0f);

  // 6. x = prelu(xcat Wp^T + bp) (f32)
  gemm_nt<3><<<256, 256, 0, stream>>>(xcat, 2048, Wpb, 2048, xf, 512, 0, bp, alpha, 4, 2048, 1.0f);

  // 7. GroupNorm
  gn_stats_kernel<<<256, 256, 0, stream>>>(xf, gp);
  gn_finalize_kernel<<<1, 64, 0, stream>>>(gp, mv);
  gn_norm_kernel<<<4096, 256, 0, stream>>>(xf, mv, gamma, beta, (float*)d_out);
}